// Round 1
// baseline (2447.999 us; speedup 1.0000x reference)
//
#include <hip/hip_runtime.h>
#include <cmath>

#define NN 147456     // H*W*A
#define NPX 16384     // H*W
#define NB 6000       // before_proposal_num
#define NA 300        // after_proposal_num
#define MW 94         // ceil(6000/64)

// ---------------- K0: conv weight permute: wT[g][ci][tap][co] = w[(g*64+co)][ci][tap]
__global__ __launch_bounds__(256) void prep_w_k(const float* __restrict__ w, float* __restrict__ wT) {
    int idx = blockIdx.x * 256 + threadIdx.x;
    if (idx >= 256 * 256 * 9) return;
    int co  = idx & 63;
    int tap = (idx >> 6) % 9;
    int ci  = (idx / 576) & 255;
    int g   = idx / (576 * 256);
    wT[idx] = w[((g * 64 + co) * 256 + ci) * 9 + tap];
}

// ---------------- K1: 3x3 conv (fp64 accumulate) + bias + relu -> h64 in CHW
__global__ __launch_bounds__(256) void conv3_k(const float* __restrict__ x, const float* __restrict__ wT,
                                               const float* __restrict__ bias, double* __restrict__ h64) {
    __shared__ double xt[8][10][10];
    __shared__ double wt[8][9][66];   // co-dim padded to 66 to spread banks a bit
    const int tile = blockIdx.x;      // 0..255 pixel tiles (8x8 px each)
    const int g = blockIdx.y;         // 0..3 cout groups of 64
    const int ty0 = (tile >> 4) << 3;
    const int tx0 = (tile & 15) << 3;
    const int tid = threadIdx.x;
    const int qc = tid & 15;          // cout quad
    const int qp = tid >> 4;          // pixel quad
    const int py = qp >> 1;           // row 0..7
    const int px4 = (qp & 1) << 2;    // col base 0 or 4
    double acc[4][4] = {};
    const float* wp0 = wT + (g * 256) * 576;
    for (int k = 0; k < 32; ++k) {
        const int ci0 = k * 8;
        __syncthreads();
        for (int l = tid; l < 800; l += 256) {
            int ci = l / 100;
            int rem = l - ci * 100;
            int rr = rem / 10;
            int cc2 = rem - rr * 10;
            int gy = ty0 + rr - 1, gx = tx0 + cc2 - 1;
            float v = 0.f;
            if (gy >= 0 && gy < 128 && gx >= 0 && gx < 128)
                v = x[(ci0 + ci) * NPX + gy * 128 + gx];
            xt[ci][rr][cc2] = (double)v;
        }
        const float* wp = wp0 + ci0 * 576;
        for (int l = tid; l < 4608; l += 256) {
            int co = l & 63;
            int tap = (l >> 6) % 9;
            int ci = l / 576;
            wt[ci][tap][co] = (double)wp[l];
        }
        __syncthreads();
        for (int ci = 0; ci < 8; ++ci) {
            #pragma unroll
            for (int dy = 0; dy < 3; ++dy) {
                double xr[6];
                #pragma unroll
                for (int jj = 0; jj < 6; ++jj) xr[jj] = xt[ci][py + dy][px4 + jj];
                #pragma unroll
                for (int dx = 0; dx < 3; ++dx) {
                    double wv[4];
                    #pragma unroll
                    for (int co = 0; co < 4; ++co) wv[co] = wt[ci][dy * 3 + dx][(qc << 2) + co];
                    #pragma unroll
                    for (int co = 0; co < 4; ++co)
                        #pragma unroll
                        for (int p = 0; p < 4; ++p)
                            acc[co][p] = fma(wv[co], xr[p + dx], acc[co][p]);
                }
            }
        }
    }
    const int oy = ty0 + py;
    #pragma unroll
    for (int co = 0; co < 4; ++co) {
        int oc = (g << 6) + (qc << 2) + co;
        double b = (double)bias[oc];
        #pragma unroll
        for (int p = 0; p < 4; ++p) {
            double v = acc[co][p] + b;
            h64[(size_t)oc * NPX + oy * 128 + tx0 + px4 + p] = v > 0.0 ? v : 0.0;
        }
    }
}

// ---------------- K2: 1x1 heads (fp64) + sigmoid; writes fp32 outs + fp64 copies
__global__ __launch_bounds__(1024) void heads_k(const double* __restrict__ h64,
        const float* __restrict__ cls_w, const float* __restrict__ cls_b,
        const float* __restrict__ bbox_w, const float* __restrict__ bbox_b,
        float* __restrict__ out_scores, float* __restrict__ out_regs,
        double* __restrict__ scores64, double* __restrict__ regs64) {
    __shared__ float wl[45 * 256];
    const int tid = threadIdx.x;
    for (int l = tid; l < 45 * 256; l += 1024)
        wl[l] = (l < 2304) ? cls_w[l] : bbox_w[l - 2304];
    __syncthreads();
    const int w = tid >> 6;
    const int lane = tid & 63;
    const int px = blockIdx.x * 64 + lane;
    const int o0 = w, o1 = w + 16, o2 = w + 32;
    const bool has2 = (o2 < 45);
    double a0 = 0.0, a1 = 0.0, a2 = 0.0;
    const float* w0 = wl + o0 * 256;
    const float* w1 = wl + o1 * 256;
    const float* w2 = wl + (has2 ? o2 : 0) * 256;
    for (int c = 0; c < 256; ++c) {
        double hv = h64[(size_t)c * NPX + px];
        a0 = fma(hv, (double)w0[c], a0);
        a1 = fma(hv, (double)w1[c], a1);
        if (has2) a2 = fma(hv, (double)w2[c], a2);
    }
    auto emit = [&](int o, double acc) {
        if (o < 9) {
            acc += (double)cls_b[o];
            double s = 1.0 / (1.0 + exp(-acc));
            out_scores[px * 9 + o] = (float)s;
            scores64[px * 9 + o] = s;
        } else {
            acc += (double)bbox_b[o - 9];
            out_regs[px * 36 + (o - 9)] = (float)acc;
            regs64[px * 36 + (o - 9)] = acc;
        }
    };
    emit(o0, a0);
    emit(o1, a1);
    if (has2) emit(o2, a2);
}

// ---------------- K3: 3-pass radix histogram on fp64 score bit patterns
__global__ __launch_bounds__(1024) void hist_k(const double* __restrict__ s64, unsigned int* __restrict__ ghist,
                                               const unsigned int* __restrict__ cut, int pass) {
    __shared__ unsigned int lh[4096];
    const int tid = threadIdx.x;
    for (int i = tid; i < 4096; i += 1024) lh[i] = 0;
    __syncthreads();
    const int gid = blockIdx.x * 1024 + tid;   // grid 144*1024 == NN exactly
    unsigned long long bits = (unsigned long long)__double_as_longlong(s64[gid]);
    bool ok; unsigned int bucket;
    if (pass == 0) {
        ok = true; bucket = (unsigned int)(bits >> 52);
    } else if (pass == 1) {
        ok = ((unsigned int)(bits >> 52) == cut[0]);
        bucket = (unsigned int)(bits >> 40) & 0xFFFu;
    } else {
        ok = (((unsigned int)(bits >> 40) & 0xFFFFFFu) == ((cut[0] << 12) | cut[2]));
        bucket = (unsigned int)(bits >> 28) & 0xFFFu;
    }
    if (ok) atomicAdd(&lh[bucket], 1u);
    __syncthreads();
    for (int i = tid; i < 4096; i += 1024) {
        unsigned int v = lh[i];
        if (v) atomicAdd(&ghist[i], v);
    }
}

// single-wave descending scan over 4096 bins: find crossing bucket for NB
__global__ __launch_bounds__(64) void scan_k(const unsigned int* __restrict__ hist,
                                             unsigned int* __restrict__ cut, int pass) {
    const int lane = threadIdx.x;
    unsigned int running = (pass == 0) ? 0u : cut[2 * pass - 1];
    for (int it = 0; it < 64; ++it) {
        int r = it * 64 + lane;
        int b = 4095 - r;
        unsigned int c = hist[b];
        unsigned int inc = c;
        #pragma unroll
        for (int d = 1; d < 64; d <<= 1) {
            unsigned int o = __shfl_up(inc, d);
            if (lane >= d) inc += o;
        }
        unsigned long long mb = __ballot(running + inc >= (unsigned int)NB);
        if (mb != 0ULL) {
            int first = __builtin_ctzll(mb);
            if (lane == first) {
                cut[2 * pass] = (unsigned int)b;
                cut[2 * pass + 1] = running + inc - c;   // strictly-above count
            }
            return;
        }
        running += __shfl(inc, 63);
    }
    if (lane == 0) { cut[2 * pass] = 0; cut[2 * pass + 1] = 0; }
}

__global__ __launch_bounds__(1024) void gather_k(const double* __restrict__ s64, const unsigned int* __restrict__ cut,
                                                 unsigned int* __restrict__ counter, unsigned int* __restrict__ cand) {
    const int gid = blockIdx.x * 1024 + threadIdx.x;
    unsigned long long bits = (unsigned long long)__double_as_longlong(s64[gid]);
    unsigned long long k36 = (bits >> 28) & 0xFFFFFFFFFULL;
    unsigned long long T = ((unsigned long long)((cut[0] << 12) | cut[2]) << 12) | (unsigned long long)cut[4];
    if (k36 >= T) {
        unsigned int p = atomicAdd(counter, 1u);
        if (p < 8192) cand[p] = (unsigned int)gid;
    }
}

// exact rank-select (score bits desc, idx asc) -> top_idx[0..NB)
__global__ __launch_bounds__(256) void rank_k(const double* __restrict__ s64, const unsigned int* __restrict__ counter,
                                              const unsigned int* __restrict__ cand, unsigned int* __restrict__ topi) {
    __shared__ unsigned long long ck[2048];
    __shared__ unsigned int cv[2048];
    int M = (int)*counter; if (M > 8192) M = 8192;
    const int gid = blockIdx.x * 256 + threadIdx.x;   // 0..8191
    unsigned long long myk = 0ULL; unsigned int myv = 0u;
    const bool act = gid < M;
    if (act) { myv = cand[gid]; myk = (unsigned long long)__double_as_longlong(s64[myv]); }
    int rank = 0;
    for (int base = 0; base < 8192; base += 2048) {
        __syncthreads();
        for (int l = threadIdx.x; l < 2048; l += 256) {
            int src = base + l;
            if (src < M) {
                unsigned int v = cand[src];
                ck[l] = (unsigned long long)__double_as_longlong(s64[v]);
                cv[l] = v;
            } else { ck[l] = 0ULL; cv[l] = 0xFFFFFFFFu; }
        }
        __syncthreads();
        if (act) {
            for (int l = 0; l < 2048; ++l) {
                unsigned long long kk = ck[l];
                if (kk > myk || (kk == myk && cv[l] < myv)) ++rank;
            }
        }
    }
    if (act && rank < NB) topi[rank] = myv;
}

// ---------------- K4: decode + clip + size filter (fp64, exact reference formulas)
__global__ __launch_bounds__(256) void decode_k(const float* __restrict__ anchors, const double* __restrict__ r64,
        const double* __restrict__ s64, const unsigned int* __restrict__ topi,
        double* __restrict__ boxes64, double* __restrict__ nsc) {
    const int r = blockIdx.x * 256 + threadIdx.x;
    if (r >= NB) return;
    const unsigned int i = topi[r];
    const int px = i / 9, a = i % 9;
    const float* an = anchors + px * 36 + a * 4;
    const double* d = r64 + px * 36 + a * 4;
    const double acy = (double)an[0], acx = (double)an[1], ah = (double)an[2], aw = (double)an[3];
    const double cy = acy + d[0] * ah;
    const double cx = acx + d[1] * aw;
    const double bh = ah * exp(d[2]);
    const double bw = aw * exp(d[3]);
    double y1 = cy - 0.5 * bh, x1 = cx - 0.5 * bw;
    double y2 = cy + 0.5 * bh, x2 = cx + 0.5 * bw;
    y1 = fmax(y1, 0.0); x1 = fmax(x1, 0.0);
    y2 = fmin(y2, 2048.0); x2 = fmin(x2, 2048.0);
    boxes64[r * 4 + 0] = y1; boxes64[r * 4 + 1] = x1;
    boxes64[r * 4 + 2] = y2; boxes64[r * 4 + 3] = x2;
    double s = s64[i];
    if (!(((y2 - y1) >= 16.0) && ((x2 - x1) >= 16.0))) s = -1.0e9;
    nsc[r] = s;
}

// ---------------- K5: suppression bitmask (upper triangle), fp64 IoU exact formula
__global__ __launch_bounds__(64) void iou_k(const double* __restrict__ boxes64, unsigned long long* __restrict__ mask) {
    const int bi = blockIdx.x, bj = blockIdx.y;
    if (bj < bi) return;                         // entire block strictly lower triangle
    __shared__ double jb[64][4];
    const int t = threadIdx.x;
    const int j0 = bj * 64;
    const int jn = min(64, NB - j0);
    if (t < jn) {
        jb[t][0] = boxes64[(j0 + t) * 4 + 0];
        jb[t][1] = boxes64[(j0 + t) * 4 + 1];
        jb[t][2] = boxes64[(j0 + t) * 4 + 2];
        jb[t][3] = boxes64[(j0 + t) * 4 + 3];
    }
    __syncthreads();
    const int i = bi * 64 + t;
    if (i >= NB) return;
    const double y1 = boxes64[i * 4 + 0], x1 = boxes64[i * 4 + 1];
    const double y2 = boxes64[i * 4 + 2], x2 = boxes64[i * 4 + 3];
    const double a1 = (y2 - y1) * (x2 - x1);
    unsigned long long wbits = 0ULL;
    for (int jj = 0; jj < jn; ++jj) {
        const int j = j0 + jj;
        if (j <= i) continue;
        const double yy1 = fmax(y1, jb[jj][0]);
        const double xx1 = fmax(x1, jb[jj][1]);
        const double yy2 = fmin(y2, jb[jj][2]);
        const double xx2 = fmin(x2, jb[jj][3]);
        const double ih = fmax(yy2 - yy1, 0.0);
        const double iw = fmax(xx2 - xx1, 0.0);
        const double inter = ih * iw;
        const double a2 = (jb[jj][2] - jb[jj][0]) * (jb[jj][3] - jb[jj][1]);
        const double iou = inter / (a1 + a2 - inter + 1e-9);
        if (iou > 0.7) wbits |= (1ULL << jj);
    }
    mask[(size_t)i * MW + bj] = wbits;
}

// ---------------- K6: sequential greedy scan over bitmask (== reference NMS scan)
__global__ __launch_bounds__(64) void nms_k(const double* __restrict__ boxes64, const double* __restrict__ nsc,
                                            const unsigned long long* __restrict__ mask, float* __restrict__ out_boxes) {
    __shared__ unsigned long long flags[MW], supp[MW];
    const int lane = threadIdx.x;
    for (int w = lane; w < MW; w += 64) supp[w] = 0ULL;
    for (int w = 0; w < MW; ++w) {
        int idx = w * 64 + lane;
        bool v = (idx < NB) && (nsc[idx] > -5.0e8);
        unsigned long long b = __ballot(v);
        if (lane == 0) flags[w] = b;
    }
    __syncthreads();
    int nk = 0;
    for (int w = 0; w < MW && nk < NA; ++w) {
        unsigned long long consumed = 0ULL;
        for (;;) {
            if (nk >= NA) break;
            unsigned long long avail = flags[w] & ~supp[w] & ~consumed;
            if (!avail) break;
            const int bit = __builtin_ctzll(avail);
            const int i = w * 64 + bit;
            consumed |= (1ULL << bit);
            if (lane < 4) out_boxes[nk * 4 + lane] = (float)boxes64[i * 4 + lane];
            ++nk;
            for (int ww = lane; ww < MW; ww += 64) supp[ww] |= mask[(size_t)i * MW + ww];
            __syncthreads();
        }
    }
    for (int k = nk; k < NA; ++k)
        if (lane < 4) out_boxes[k * 4 + lane] = 0.f;
}

extern "C" void kernel_launch(void* const* d_in, const int* in_sizes, int n_in,
                              void* d_out, int out_size, void* d_ws, size_t ws_size,
                              hipStream_t stream) {
    (void)in_sizes; (void)n_in; (void)out_size; (void)ws_size;
    const float* x       = (const float*)d_in[0];
    const float* anchors = (const float*)d_in[1];
    const float* conv1_w = (const float*)d_in[2];
    const float* conv1_b = (const float*)d_in[3];
    const float* cls_w   = (const float*)d_in[4];
    const float* cls_b   = (const float*)d_in[5];
    const float* bbox_w  = (const float*)d_in[6];
    const float* bbox_b  = (const float*)d_in[7];
    float* out = (float*)d_out;
    float* out_scores = out;             // 147456
    float* out_regs   = out + NN;        // 589824
    float* out_boxes  = out + NN * 5;    // 1200 @ 737280

    char* ws = (char*)d_ws;
    // Overlay region: lives inside the h64 footprint; only used after heads_k (h dead).
    unsigned int* hist        = (unsigned int*)(ws + 0);          // 16384 B
    unsigned int* cut         = (unsigned int*)(ws + 16384);      // 64 B
    unsigned int* cnt         = (unsigned int*)(ws + 16640);      // 256 B
    unsigned int* cand        = (unsigned int*)(ws + 16896);      // 32768 B
    unsigned int* topi        = (unsigned int*)(ws + 49664);      // 24064 B
    double*       boxes64     = (double*)(ws + 73728);            // 192000 B
    double*       nsc         = (double*)(ws + 265728);           // 48000 B
    unsigned long long* mask  = (unsigned long long*)(ws + 313856); // 4512000 B (< 33.5 MB)
    double* h64 = (double*)(ws + 0);                              // 33554432 B
    float*  wT  = (float*)(ws + 33554432);                        // 2359296 B
    double* s64 = (double*)(ws + 35913728);                       // 1179648 B
    double* r64 = (double*)(ws + 37093376);                       // 4718592 B  (total ~39.9 MB)

    prep_w_k<<<2304, 256, 0, stream>>>(conv1_w, wT);
    conv3_k<<<dim3(256, 4), 256, 0, stream>>>(x, wT, conv1_b, h64);
    heads_k<<<256, 1024, 0, stream>>>(h64, cls_w, cls_b, bbox_w, bbox_b,
                                      out_scores, out_regs, s64, r64);
    // h64 is dead from here; overlay region becomes valid.
    hipMemsetAsync(cnt, 0, 4, stream);
    for (int pass = 0; pass < 3; ++pass) {
        hipMemsetAsync(hist, 0, 16384, stream);
        hist_k<<<144, 1024, 0, stream>>>(s64, hist, cut, pass);
        scan_k<<<1, 64, 0, stream>>>(hist, cut, pass);
    }
    gather_k<<<144, 1024, 0, stream>>>(s64, cut, cnt, cand);
    rank_k<<<32, 256, 0, stream>>>(s64, cnt, cand, topi);
    decode_k<<<24, 256, 0, stream>>>(anchors, r64, s64, topi, boxes64, nsc);
    hipMemsetAsync(mask, 0, (size_t)NB * MW * 8, stream);
    iou_k<<<dim3(MW, MW), 64, 0, stream>>>(boxes64, mask);
    nms_k<<<1, 64, 0, stream>>>(boxes64, nsc, mask, out_boxes);
}

// Round 4
// 1826.918 us; speedup vs baseline: 1.3400x; 1.3400x over previous
//
#include <hip/hip_runtime.h>
#include <cmath>

#define NN 147456     // H*W*A
#define NPX 16384     // H*W
#define NB 6000       // before_proposal_num
#define NA 300        // after_proposal_num
#define MW 94         // ceil(6000/64)

// ---------------- K0: conv weight permute: wT[g][ci][tap][co] = w[(g*64+co)][ci][tap]
// (round-1 proven version)
__global__ __launch_bounds__(256) void prep_w_k(const float* __restrict__ w, float* __restrict__ wT) {
    int idx = blockIdx.x * 256 + threadIdx.x;
    if (idx >= 256 * 256 * 9) return;
    int co  = idx & 63;
    int tap = (idx >> 6) % 9;
    int ci  = (idx / 576) & 255;
    int g   = idx / (576 * 256);
    wT[idx] = w[((g * 64 + co) * 256 + ci) * 9 + tap];
}

// ---------------- K1: 3x3 conv (fp64 fma, round-1 arithmetic ORDER bit-identical)
// LDS weight layout changed to [ci][tap][16 slots x 5 doubles] (slot stride 40B)
// to kill the 4-way bank conflict measured in round 1 (SQ_LDS_BANK_CONFLICT=4.5e8):
// old stride 32B -> banks (qc*8)%32 collide 4-way; new 40B -> (qc*10)%32 all distinct.
__global__ __launch_bounds__(256) void conv3_k(const float* __restrict__ x, const float* __restrict__ wT,
                                               const float* __restrict__ bias, double* __restrict__ h64) {
    __shared__ double xt[8][10][10];
    __shared__ double wt[8 * 9 * 80];   // [ci][tap][qc*5 + cr], 46080 B
    const int tile = blockIdx.x;        // 0..255 pixel tiles (8x8 px each)
    const int g = blockIdx.y;           // 0..3 cout groups of 64
    const int ty0 = (tile >> 4) << 3;
    const int tx0 = (tile & 15) << 3;
    const int tid = threadIdx.x;
    const int qc = tid & 15;            // cout quad
    const int qp = tid >> 4;            // pixel quad
    const int py = qp >> 1;             // row 0..7
    const int px4 = (qp & 1) << 2;      // col base 0 or 4
    double acc[4][4] = {};
    const float* wp0 = wT + (g * 256) * 576;
    for (int k = 0; k < 32; ++k) {
        const int ci0 = k * 8;
        __syncthreads();
        for (int l = tid; l < 800; l += 256) {
            int ci = l / 100;
            int rem = l - ci * 100;
            int rr = rem / 10;
            int cc2 = rem - rr * 10;
            int gy = ty0 + rr - 1, gx = tx0 + cc2 - 1;
            float v = 0.f;
            if (gy >= 0 && gy < 128 && gx >= 0 && gx < 128)
                v = x[(ci0 + ci) * NPX + gy * 128 + gx];
            xt[ci][rr][cc2] = (double)v;
        }
        const float* wp = wp0 + ci0 * 576;
        for (int l = tid; l < 4608; l += 256) {
            int co = l & 63;
            int tap = (l >> 6) % 9;
            int ci = l / 576;
            wt[(ci * 9 + tap) * 80 + (co >> 2) * 5 + (co & 3)] = (double)wp[l];
        }
        __syncthreads();
        for (int ci = 0; ci < 8; ++ci) {
            #pragma unroll
            for (int dy = 0; dy < 3; ++dy) {
                double xr[6];
                #pragma unroll
                for (int jj = 0; jj < 6; ++jj) xr[jj] = xt[ci][py + dy][px4 + jj];
                #pragma unroll
                for (int dx = 0; dx < 3; ++dx) {
                    double wv[4];
                    #pragma unroll
                    for (int co = 0; co < 4; ++co)
                        wv[co] = wt[(ci * 9 + dy * 3 + dx) * 80 + qc * 5 + co];
                    #pragma unroll
                    for (int co = 0; co < 4; ++co)
                        #pragma unroll
                        for (int p = 0; p < 4; ++p)
                            acc[co][p] = fma(wv[co], xr[p + dx], acc[co][p]);
                }
            }
        }
    }
    const int oy = ty0 + py;
    #pragma unroll
    for (int co = 0; co < 4; ++co) {
        int oc = (g << 6) + (qc << 2) + co;
        double b = (double)bias[oc];
        #pragma unroll
        for (int p = 0; p < 4; ++p) {
            double v = acc[co][p] + b;
            h64[(size_t)oc * NPX + oy * 128 + tx0 + px4 + p] = v > 0.0 ? v : 0.0;
        }
    }
}

// ---------------- K2: 1x1 heads (fp64) + sigmoid; writes fp32 outs + fp64 copies
__global__ __launch_bounds__(1024) void heads_k(const double* __restrict__ h64,
        const float* __restrict__ cls_w, const float* __restrict__ cls_b,
        const float* __restrict__ bbox_w, const float* __restrict__ bbox_b,
        float* __restrict__ out_scores, float* __restrict__ out_regs,
        double* __restrict__ scores64, double* __restrict__ regs64) {
    __shared__ float wl[45 * 256];
    const int tid = threadIdx.x;
    for (int l = tid; l < 45 * 256; l += 1024)
        wl[l] = (l < 2304) ? cls_w[l] : bbox_w[l - 2304];
    __syncthreads();
    const int w = tid >> 6;
    const int lane = tid & 63;
    const int px = blockIdx.x * 64 + lane;
    const int o0 = w, o1 = w + 16, o2 = w + 32;
    const bool has2 = (o2 < 45);
    double a0 = 0.0, a1 = 0.0, a2 = 0.0;
    const float* w0 = wl + o0 * 256;
    const float* w1 = wl + o1 * 256;
    const float* w2 = wl + (has2 ? o2 : 0) * 256;
    for (int c = 0; c < 256; ++c) {
        double hv = h64[(size_t)c * NPX + px];
        a0 = fma(hv, (double)w0[c], a0);
        a1 = fma(hv, (double)w1[c], a1);
        if (has2) a2 = fma(hv, (double)w2[c], a2);
    }
    auto emit = [&](int o, double acc) {
        if (o < 9) {
            acc += (double)cls_b[o];
            double s = 1.0 / (1.0 + exp(-acc));
            out_scores[px * 9 + o] = (float)s;
            scores64[px * 9 + o] = s;
        } else {
            acc += (double)bbox_b[o - 9];
            out_regs[px * 36 + (o - 9)] = (float)acc;
            regs64[px * 36 + (o - 9)] = acc;
        }
    };
    emit(o0, a0);
    emit(o1, a1);
    if (has2) emit(o2, a2);
}

// ---------------- K3: 3-pass radix histogram on fp64 score bit patterns
__global__ __launch_bounds__(1024) void hist_k(const double* __restrict__ s64, unsigned int* __restrict__ ghist,
                                               const unsigned int* __restrict__ cut, int pass) {
    __shared__ unsigned int lh[4096];
    const int tid = threadIdx.x;
    for (int i = tid; i < 4096; i += 1024) lh[i] = 0;
    __syncthreads();
    const int gid = blockIdx.x * 1024 + tid;   // grid 144*1024 == NN exactly
    unsigned long long bits = (unsigned long long)__double_as_longlong(s64[gid]);
    bool ok; unsigned int bucket;
    if (pass == 0) {
        ok = true; bucket = (unsigned int)(bits >> 52);
    } else if (pass == 1) {
        ok = ((unsigned int)(bits >> 52) == cut[0]);
        bucket = (unsigned int)(bits >> 40) & 0xFFFu;
    } else {
        ok = (((unsigned int)(bits >> 40) & 0xFFFFFFu) == ((cut[0] << 12) | cut[2]));
        bucket = (unsigned int)(bits >> 28) & 0xFFFu;
    }
    if (ok) atomicAdd(&lh[bucket], 1u);
    __syncthreads();
    for (int i = tid; i < 4096; i += 1024) {
        unsigned int v = lh[i];
        if (v) atomicAdd(&ghist[i], v);
    }
}

// single-wave descending scan over 4096 bins: find crossing bucket for NB
__global__ __launch_bounds__(64) void scan_k(const unsigned int* __restrict__ hist,
                                             unsigned int* __restrict__ cut, int pass) {
    const int lane = threadIdx.x;
    unsigned int running = (pass == 0) ? 0u : cut[2 * pass - 1];
    for (int it = 0; it < 64; ++it) {
        int r = it * 64 + lane;
        int b = 4095 - r;
        unsigned int c = hist[b];
        unsigned int inc = c;
        #pragma unroll
        for (int d = 1; d < 64; d <<= 1) {
            unsigned int o = __shfl_up(inc, d);
            if (lane >= d) inc += o;
        }
        unsigned long long mb = __ballot(running + inc >= (unsigned int)NB);
        if (mb != 0ULL) {
            int first = __builtin_ctzll(mb);
            if (lane == first) {
                cut[2 * pass] = (unsigned int)b;
                cut[2 * pass + 1] = running + inc - c;   // strictly-above count
            }
            return;
        }
        running += __shfl(inc, 63);
    }
    if (lane == 0) { cut[2 * pass] = 0; cut[2 * pass + 1] = 0; }
}

__global__ __launch_bounds__(1024) void gather_k(const double* __restrict__ s64, const unsigned int* __restrict__ cut,
                                                 unsigned int* __restrict__ counter, unsigned int* __restrict__ cand) {
    const int gid = blockIdx.x * 1024 + threadIdx.x;
    unsigned long long bits = (unsigned long long)__double_as_longlong(s64[gid]);
    unsigned long long k36 = (bits >> 28) & 0xFFFFFFFFFULL;
    unsigned long long T = ((unsigned long long)((cut[0] << 12) | cut[2]) << 12) | (unsigned long long)cut[4];
    if (k36 >= T) {
        unsigned int p = atomicAdd(counter, 1u);
        if (p < 8192) cand[p] = (unsigned int)gid;
    }
}

// exact rank-select (score bits desc, idx asc) -> top_idx[0..NB)   [round-1 proven version]
__global__ __launch_bounds__(256) void rank_k(const double* __restrict__ s64, const unsigned int* __restrict__ counter,
                                              const unsigned int* __restrict__ cand, unsigned int* __restrict__ topi) {
    __shared__ unsigned long long ck[2048];
    __shared__ unsigned int cv[2048];
    int M = (int)*counter; if (M > 8192) M = 8192;
    const int gid = blockIdx.x * 256 + threadIdx.x;   // 0..8191
    unsigned long long myk = 0ULL; unsigned int myv = 0u;
    const bool act = gid < M;
    if (act) { myv = cand[gid]; myk = (unsigned long long)__double_as_longlong(s64[myv]); }
    int rank = 0;
    for (int base = 0; base < 8192; base += 2048) {
        __syncthreads();
        for (int l = threadIdx.x; l < 2048; l += 256) {
            int src = base + l;
            if (src < M) {
                unsigned int v = cand[src];
                ck[l] = (unsigned long long)__double_as_longlong(s64[v]);
                cv[l] = v;
            } else { ck[l] = 0ULL; cv[l] = 0xFFFFFFFFu; }
        }
        __syncthreads();
        if (act) {
            for (int l = 0; l < 2048; ++l) {
                unsigned long long kk = ck[l];
                if (kk > myk || (kk == myk && cv[l] < myv)) ++rank;
            }
        }
    }
    if (act && rank < NB) topi[rank] = myv;
}

// ---------------- K4: decode + clip + size filter (fp64, exact reference formulas)
__global__ __launch_bounds__(256) void decode_k(const float* __restrict__ anchors, const double* __restrict__ r64,
        const double* __restrict__ s64, const unsigned int* __restrict__ topi,
        double* __restrict__ boxes64, double* __restrict__ nsc) {
    const int r = blockIdx.x * 256 + threadIdx.x;
    if (r >= NB) return;
    const unsigned int i = topi[r];
    const int px = i / 9, a = i % 9;
    const float* an = anchors + px * 36 + a * 4;
    const double* d = r64 + px * 36 + a * 4;
    const double acy = (double)an[0], acx = (double)an[1], ah = (double)an[2], aw = (double)an[3];
    const double cy = acy + d[0] * ah;
    const double cx = acx + d[1] * aw;
    const double bh = ah * exp(d[2]);
    const double bw = aw * exp(d[3]);
    double y1 = cy - 0.5 * bh, x1 = cx - 0.5 * bw;
    double y2 = cy + 0.5 * bh, x2 = cx + 0.5 * bw;
    y1 = fmax(y1, 0.0); x1 = fmax(x1, 0.0);
    y2 = fmin(y2, 2048.0); x2 = fmin(x2, 2048.0);
    boxes64[r * 4 + 0] = y1; boxes64[r * 4 + 1] = x1;
    boxes64[r * 4 + 2] = y2; boxes64[r * 4 + 3] = x2;
    double s = s64[i];
    if (!(((y2 - y1) >= 16.0) && ((x2 - x1) >= 16.0))) s = -1.0e9;
    nsc[r] = s;
}

// ---------------- K5: suppression bitmask (upper triangle), fp64 IoU exact formula
__global__ __launch_bounds__(64) void iou_k(const double* __restrict__ boxes64, unsigned long long* __restrict__ mask) {
    const int bi = blockIdx.x, bj = blockIdx.y;
    if (bj < bi) return;
    __shared__ double jb[64][4];
    const int t = threadIdx.x;
    const int j0 = bj * 64;
    const int jn = min(64, NB - j0);
    if (t < jn) {
        jb[t][0] = boxes64[(j0 + t) * 4 + 0];
        jb[t][1] = boxes64[(j0 + t) * 4 + 1];
        jb[t][2] = boxes64[(j0 + t) * 4 + 2];
        jb[t][3] = boxes64[(j0 + t) * 4 + 3];
    }
    __syncthreads();
    const int i = bi * 64 + t;
    if (i >= NB) return;
    const double y1 = boxes64[i * 4 + 0], x1 = boxes64[i * 4 + 1];
    const double y2 = boxes64[i * 4 + 2], x2 = boxes64[i * 4 + 3];
    const double a1 = (y2 - y1) * (x2 - x1);
    unsigned long long wbits = 0ULL;
    for (int jj = 0; jj < jn; ++jj) {
        const int j = j0 + jj;
        if (j <= i) continue;
        const double yy1 = fmax(y1, jb[jj][0]);
        const double xx1 = fmax(x1, jb[jj][1]);
        const double yy2 = fmin(y2, jb[jj][2]);
        const double xx2 = fmin(x2, jb[jj][3]);
        const double ih = fmax(yy2 - yy1, 0.0);
        const double iw = fmax(xx2 - xx1, 0.0);
        const double inter = ih * iw;
        const double a2 = (jb[jj][2] - jb[jj][0]) * (jb[jj][3] - jb[jj][1]);
        const double iou = inter / (a1 + a2 - inter + 1e-9);
        if (iou > 0.7) wbits |= (1ULL << jj);
    }
    mask[(size_t)i * MW + bj] = wbits;
}

// ---------------- K6: sequential greedy scan over bitmask (== reference NMS scan)
__global__ __launch_bounds__(64) void nms_k(const double* __restrict__ boxes64, const double* __restrict__ nsc,
                                            const unsigned long long* __restrict__ mask, float* __restrict__ out_boxes) {
    __shared__ unsigned long long flags[MW], supp[MW];
    const int lane = threadIdx.x;
    for (int w = lane; w < MW; w += 64) supp[w] = 0ULL;
    for (int w = 0; w < MW; ++w) {
        int idx = w * 64 + lane;
        bool v = (idx < NB) && (nsc[idx] > -5.0e8);
        unsigned long long b = __ballot(v);
        if (lane == 0) flags[w] = b;
    }
    __syncthreads();
    int nk = 0;
    for (int w = 0; w < MW && nk < NA; ++w) {
        unsigned long long consumed = 0ULL;
        for (;;) {
            if (nk >= NA) break;
            unsigned long long avail = flags[w] & ~supp[w] & ~consumed;
            if (!avail) break;
            const int bit = __builtin_ctzll(avail);
            const int i = w * 64 + bit;
            consumed |= (1ULL << bit);
            if (lane < 4) out_boxes[nk * 4 + lane] = (float)boxes64[i * 4 + lane];
            ++nk;
            for (int ww = lane; ww < MW; ww += 64) supp[ww] |= mask[(size_t)i * MW + ww];
            __syncthreads();
        }
    }
    for (int k = nk; k < NA; ++k)
        if (lane < 4) out_boxes[k * 4 + lane] = 0.f;
}

extern "C" void kernel_launch(void* const* d_in, const int* in_sizes, int n_in,
                              void* d_out, int out_size, void* d_ws, size_t ws_size,
                              hipStream_t stream) {
    (void)in_sizes; (void)n_in; (void)out_size; (void)ws_size;
    const float* x       = (const float*)d_in[0];
    const float* anchors = (const float*)d_in[1];
    const float* conv1_w = (const float*)d_in[2];
    const float* conv1_b = (const float*)d_in[3];
    const float* cls_w   = (const float*)d_in[4];
    const float* cls_b   = (const float*)d_in[5];
    const float* bbox_w  = (const float*)d_in[6];
    const float* bbox_b  = (const float*)d_in[7];
    float* out = (float*)d_out;
    float* out_scores = out;             // 147456
    float* out_regs   = out + NN;        // 589824
    float* out_boxes  = out + NN * 5;    // 1200 @ 737280

    char* ws = (char*)d_ws;
    // Overlay region inside the h64 footprint; only used after heads_k (h dead).
    unsigned int* hist        = (unsigned int*)(ws + 0);            // 16384 B
    unsigned int* cut         = (unsigned int*)(ws + 16384);        // 64 B
    unsigned int* cnt         = (unsigned int*)(ws + 16640);        // 256 B
    unsigned int* cand        = (unsigned int*)(ws + 16896);        // 32768 B
    unsigned int* topi        = (unsigned int*)(ws + 49664);        // 24064 B
    double*       boxes64     = (double*)(ws + 73728);              // 192000 B
    double*       nsc         = (double*)(ws + 265728);             // 48000 B
    unsigned long long* mask  = (unsigned long long*)(ws + 313856); // 4512000 B
    double* h64 = (double*)(ws + 0);                                // 33554432 B
    float*  wT  = (float*)(ws + 33554432);                          // 2359296 B
    double* s64 = (double*)(ws + 35913728);                         // 1179648 B
    double* r64 = (double*)(ws + 37093376);                         // 4718592 B

    prep_w_k<<<2304, 256, 0, stream>>>(conv1_w, wT);
    conv3_k<<<dim3(256, 4), 256, 0, stream>>>(x, wT, conv1_b, h64);
    heads_k<<<256, 1024, 0, stream>>>(h64, cls_w, cls_b, bbox_w, bbox_b,
                                      out_scores, out_regs, s64, r64);
    // h64 is dead from here; overlay region becomes valid.
    hipMemsetAsync(cnt, 0, 4, stream);
    for (int pass = 0; pass < 3; ++pass) {
        hipMemsetAsync(hist, 0, 16384, stream);
        hist_k<<<144, 1024, 0, stream>>>(s64, hist, cut, pass);
        scan_k<<<1, 64, 0, stream>>>(hist, cut, pass);
    }
    gather_k<<<144, 1024, 0, stream>>>(s64, cut, cnt, cand);
    rank_k<<<32, 256, 0, stream>>>(s64, cnt, cand, topi);
    decode_k<<<24, 256, 0, stream>>>(anchors, r64, s64, topi, boxes64, nsc);
    hipMemsetAsync(mask, 0, (size_t)NB * MW * 8, stream);
    iou_k<<<dim3(MW, MW), 64, 0, stream>>>(boxes64, mask);
    nms_k<<<1, 64, 0, stream>>>(boxes64, nsc, mask, out_boxes);
}

// Round 5
// 1128.347 us; speedup vs baseline: 2.1695x; 1.6191x over previous
//
#include <hip/hip_runtime.h>
#include <cmath>

#define NN 147456     // H*W*A
#define NPX 16384     // H*W
#define NB 6000       // before_proposal_num
#define NA 300        // after_proposal_num
#define MW 94         // ceil(6000/64)

// ---------------- K0: conv weight permute: wT[g][ci][tap][co] = w[(g*64+co)][ci][tap]
__global__ __launch_bounds__(256) void prep_w_k(const float* __restrict__ w, float* __restrict__ wT) {
    int idx = blockIdx.x * 256 + threadIdx.x;
    if (idx >= 256 * 256 * 9) return;
    int co  = idx & 63;
    int tap = (idx >> 6) % 9;
    int ci  = (idx / 576) & 255;
    int g   = idx / (576 * 256);
    wT[idx] = w[((g * 64 + co) * 256 + ci) * 9 + tap];
}

// ---------------- K1: 3x3 conv (fp64 fma; arithmetic ORDER bit-identical to round 4)
// Changes vs round 4 (both value-exact):
//  * LDS tiles stored as float (inputs are fp32 -> float->double cvt is exact):
//    LDS 52.7KB -> 26.2KB -> 6 blocks/CU (occupancy 26% -> ~60%+).
//  * block swizzle: a tile's 4 g-blocks are dispatched consecutively onto the SAME
//    XCD (round-robin => bx&7 = xcd), so the x-halo is read from HBM once, not 4x
//    (round-4 FETCH was 174MB vs ~45MB ideal).
__global__ __launch_bounds__(256) void conv3_k(const float* __restrict__ x, const float* __restrict__ wT,
                                               const float* __restrict__ bias, double* __restrict__ h64) {
    __shared__ float xt[8][10][10];
    __shared__ float wt[8 * 9 * 80];    // [ci][tap][qc*5 + cr], slot stride 20B keeps banks spread
    const int bx = blockIdx.x;          // 0..1023
    const int tile = ((bx >> 5) << 3) | (bx & 7);   // 0..255
    const int g = (bx >> 3) & 3;                    // 0..3
    const int ty0 = (tile >> 4) << 3;
    const int tx0 = (tile & 15) << 3;
    const int tid = threadIdx.x;
    const int qc = tid & 15;            // cout quad
    const int qp = tid >> 4;            // pixel quad
    const int py = qp >> 1;             // row 0..7
    const int px4 = (qp & 1) << 2;      // col base 0 or 4
    double acc[4][4] = {};
    const float* wp0 = wT + (g * 256) * 576;
    for (int k = 0; k < 32; ++k) {
        const int ci0 = k * 8;
        __syncthreads();
        for (int l = tid; l < 800; l += 256) {
            int ci = l / 100;
            int rem = l - ci * 100;
            int rr = rem / 10;
            int cc2 = rem - rr * 10;
            int gy = ty0 + rr - 1, gx = tx0 + cc2 - 1;
            float v = 0.f;
            if (gy >= 0 && gy < 128 && gx >= 0 && gx < 128)
                v = x[(ci0 + ci) * NPX + gy * 128 + gx];
            xt[ci][rr][cc2] = v;
        }
        const float* wp = wp0 + ci0 * 576;
        for (int l = tid; l < 4608; l += 256) {
            int co = l & 63;
            int tap = (l >> 6) % 9;
            int ci = l / 576;
            wt[(ci * 9 + tap) * 80 + (co >> 2) * 5 + (co & 3)] = wp[l];
        }
        __syncthreads();
        for (int ci = 0; ci < 8; ++ci) {
            #pragma unroll
            for (int dy = 0; dy < 3; ++dy) {
                double xr[6];
                #pragma unroll
                for (int jj = 0; jj < 6; ++jj) xr[jj] = (double)xt[ci][py + dy][px4 + jj];
                #pragma unroll
                for (int dx = 0; dx < 3; ++dx) {
                    double wv[4];
                    #pragma unroll
                    for (int co = 0; co < 4; ++co)
                        wv[co] = (double)wt[(ci * 9 + dy * 3 + dx) * 80 + qc * 5 + co];
                    #pragma unroll
                    for (int co = 0; co < 4; ++co)
                        #pragma unroll
                        for (int p = 0; p < 4; ++p)
                            acc[co][p] = fma(wv[co], xr[p + dx], acc[co][p]);
                }
            }
        }
    }
    const int oy = ty0 + py;
    #pragma unroll
    for (int co = 0; co < 4; ++co) {
        int oc = (g << 6) + (qc << 2) + co;
        double b = (double)bias[oc];
        #pragma unroll
        for (int p = 0; p < 4; ++p) {
            double v = acc[co][p] + b;
            h64[(size_t)oc * NPX + oy * 128 + tx0 + px4 + p] = v > 0.0 ? v : 0.0;
        }
    }
}

// ---------------- K2: 1x1 heads (fp64) + sigmoid; writes fp32 outs + fp64 copies
__global__ __launch_bounds__(1024) void heads_k(const double* __restrict__ h64,
        const float* __restrict__ cls_w, const float* __restrict__ cls_b,
        const float* __restrict__ bbox_w, const float* __restrict__ bbox_b,
        float* __restrict__ out_scores, float* __restrict__ out_regs,
        double* __restrict__ scores64, double* __restrict__ regs64) {
    __shared__ float wl[45 * 256];
    const int tid = threadIdx.x;
    for (int l = tid; l < 45 * 256; l += 1024)
        wl[l] = (l < 2304) ? cls_w[l] : bbox_w[l - 2304];
    __syncthreads();
    const int w = tid >> 6;
    const int lane = tid & 63;
    const int px = blockIdx.x * 64 + lane;
    const int o0 = w, o1 = w + 16, o2 = w + 32;
    const bool has2 = (o2 < 45);
    double a0 = 0.0, a1 = 0.0, a2 = 0.0;
    const float* w0 = wl + o0 * 256;
    const float* w1 = wl + o1 * 256;
    const float* w2 = wl + (has2 ? o2 : 0) * 256;
    for (int c = 0; c < 256; ++c) {
        double hv = h64[(size_t)c * NPX + px];
        a0 = fma(hv, (double)w0[c], a0);
        a1 = fma(hv, (double)w1[c], a1);
        if (has2) a2 = fma(hv, (double)w2[c], a2);
    }
    auto emit = [&](int o, double acc) {
        if (o < 9) {
            acc += (double)cls_b[o];
            double s = 1.0 / (1.0 + exp(-acc));
            out_scores[px * 9 + o] = (float)s;
            scores64[px * 9 + o] = s;
        } else {
            acc += (double)bbox_b[o - 9];
            out_regs[px * 36 + (o - 9)] = (float)acc;
            regs64[px * 36 + (o - 9)] = acc;
        }
    };
    emit(o0, a0);
    emit(o1, a1);
    if (has2) emit(o2, a2);
}

// ---------------- K3: 3-pass radix histogram on fp64 score bit patterns
__global__ __launch_bounds__(1024) void hist_k(const double* __restrict__ s64, unsigned int* __restrict__ ghist,
                                               const unsigned int* __restrict__ cut, int pass) {
    __shared__ unsigned int lh[4096];
    const int tid = threadIdx.x;
    for (int i = tid; i < 4096; i += 1024) lh[i] = 0;
    __syncthreads();
    const int gid = blockIdx.x * 1024 + tid;   // grid 144*1024 == NN exactly
    unsigned long long bits = (unsigned long long)__double_as_longlong(s64[gid]);
    bool ok; unsigned int bucket;
    if (pass == 0) {
        ok = true; bucket = (unsigned int)(bits >> 52);
    } else if (pass == 1) {
        ok = ((unsigned int)(bits >> 52) == cut[0]);
        bucket = (unsigned int)(bits >> 40) & 0xFFFu;
    } else {
        ok = (((unsigned int)(bits >> 40) & 0xFFFFFFu) == ((cut[0] << 12) | cut[2]));
        bucket = (unsigned int)(bits >> 28) & 0xFFFu;
    }
    if (ok) atomicAdd(&lh[bucket], 1u);
    __syncthreads();
    for (int i = tid; i < 4096; i += 1024) {
        unsigned int v = lh[i];
        if (v) atomicAdd(&ghist[i], v);
    }
}

// single-wave descending scan over 4096 bins: find crossing bucket for NB
__global__ __launch_bounds__(64) void scan_k(const unsigned int* __restrict__ hist,
                                             unsigned int* __restrict__ cut, int pass) {
    const int lane = threadIdx.x;
    unsigned int running = (pass == 0) ? 0u : cut[2 * pass - 1];
    for (int it = 0; it < 64; ++it) {
        int r = it * 64 + lane;
        int b = 4095 - r;
        unsigned int c = hist[b];
        unsigned int inc = c;
        #pragma unroll
        for (int d = 1; d < 64; d <<= 1) {
            unsigned int o = __shfl_up(inc, d);
            if (lane >= d) inc += o;
        }
        unsigned long long mb = __ballot(running + inc >= (unsigned int)NB);
        if (mb != 0ULL) {
            int first = __builtin_ctzll(mb);
            if (lane == first) {
                cut[2 * pass] = (unsigned int)b;
                cut[2 * pass + 1] = running + inc - c;   // strictly-above count
            }
            return;
        }
        running += __shfl(inc, 63);
    }
    if (lane == 0) { cut[2 * pass] = 0; cut[2 * pass + 1] = 0; }
}

__global__ __launch_bounds__(1024) void gather_k(const double* __restrict__ s64, const unsigned int* __restrict__ cut,
                                                 unsigned int* __restrict__ counter, unsigned int* __restrict__ cand) {
    const int gid = blockIdx.x * 1024 + threadIdx.x;
    unsigned long long bits = (unsigned long long)__double_as_longlong(s64[gid]);
    unsigned long long k36 = (bits >> 28) & 0xFFFFFFFFFULL;
    unsigned long long T = ((unsigned long long)((cut[0] << 12) | cut[2]) << 12) | (unsigned long long)cut[4];
    if (k36 >= T) {
        unsigned int p = atomicAdd(counter, 1u);
        if (p < 8192) cand[p] = (unsigned int)gid;
    }
}

// pack candidate keys contiguously (coalesced input for rank2_k)
__global__ __launch_bounds__(256) void pack_k(const double* __restrict__ s64, const unsigned int* __restrict__ cand,
                                              const unsigned int* __restrict__ counter, unsigned long long* __restrict__ ckey) {
    int gid = blockIdx.x * 256 + threadIdx.x;
    if (gid >= 8192) return;
    int M = (int)*counter; if (M > 8192) M = 8192;
    ckey[gid] = (gid < M) ? (unsigned long long)__double_as_longlong(s64[cand[gid]]) : 0ULL;
}

// exact rank-select, one candidate per WAVE (64-lane parallel compare scan).
// Same comparator as the round-4 rank_k: (key desc, idx asc) -> unique rank.
__global__ __launch_bounds__(256) void rank2_k(const unsigned long long* __restrict__ ckey,
                                               const unsigned int* __restrict__ cand,
                                               const unsigned int* __restrict__ counter,
                                               unsigned int* __restrict__ topi) {
    int M = (int)*counter; if (M > 8192) M = 8192;
    const int wid = (blockIdx.x * 256 + threadIdx.x) >> 6;
    const int lane = threadIdx.x & 63;
    if (wid >= M) return;
    const unsigned long long myk = ckey[wid];
    const unsigned int myv = cand[wid];
    int cnt = 0;
    for (int l = lane; l < M; l += 64) {
        unsigned long long kk = ckey[l];
        unsigned int vv = cand[l];
        if (kk > myk || (kk == myk && vv < myv)) ++cnt;
    }
    #pragma unroll
    for (int d = 32; d; d >>= 1) cnt += __shfl_down(cnt, d);
    if (lane == 0 && cnt < NB) topi[cnt] = myv;
}

// ---------------- K4: decode + clip + size filter (fp64, exact reference formulas)
__global__ __launch_bounds__(256) void decode_k(const float* __restrict__ anchors, const double* __restrict__ r64,
        const double* __restrict__ s64, const unsigned int* __restrict__ topi,
        double* __restrict__ boxes64, double* __restrict__ nsc) {
    const int r = blockIdx.x * 256 + threadIdx.x;
    if (r >= NB) return;
    const unsigned int i = topi[r];
    const int px = i / 9, a = i % 9;
    const float* an = anchors + px * 36 + a * 4;
    const double* d = r64 + px * 36 + a * 4;
    const double acy = (double)an[0], acx = (double)an[1], ah = (double)an[2], aw = (double)an[3];
    const double cy = acy + d[0] * ah;
    const double cx = acx + d[1] * aw;
    const double bh = ah * exp(d[2]);
    const double bw = aw * exp(d[3]);
    double y1 = cy - 0.5 * bh, x1 = cx - 0.5 * bw;
    double y2 = cy + 0.5 * bh, x2 = cx + 0.5 * bw;
    y1 = fmax(y1, 0.0); x1 = fmax(x1, 0.0);
    y2 = fmin(y2, 2048.0); x2 = fmin(x2, 2048.0);
    boxes64[r * 4 + 0] = y1; boxes64[r * 4 + 1] = x1;
    boxes64[r * 4 + 2] = y2; boxes64[r * 4 + 3] = x2;
    double s = s64[i];
    if (!(((y2 - y1) >= 16.0) && ((x2 - x1) >= 16.0))) s = -1.0e9;
    nsc[r] = s;
}

// ---------------- K5: suppression bitmask (upper triangle), fp64 IoU exact formula
__global__ __launch_bounds__(64) void iou_k(const double* __restrict__ boxes64, unsigned long long* __restrict__ mask) {
    const int bi = blockIdx.x, bj = blockIdx.y;
    if (bj < bi) return;
    __shared__ double jb[64][4];
    const int t = threadIdx.x;
    const int j0 = bj * 64;
    const int jn = min(64, NB - j0);
    if (t < jn) {
        jb[t][0] = boxes64[(j0 + t) * 4 + 0];
        jb[t][1] = boxes64[(j0 + t) * 4 + 1];
        jb[t][2] = boxes64[(j0 + t) * 4 + 2];
        jb[t][3] = boxes64[(j0 + t) * 4 + 3];
    }
    __syncthreads();
    const int i = bi * 64 + t;
    if (i >= NB) return;
    const double y1 = boxes64[i * 4 + 0], x1 = boxes64[i * 4 + 1];
    const double y2 = boxes64[i * 4 + 2], x2 = boxes64[i * 4 + 3];
    const double a1 = (y2 - y1) * (x2 - x1);
    unsigned long long wbits = 0ULL;
    for (int jj = 0; jj < jn; ++jj) {
        const int j = j0 + jj;
        if (j <= i) continue;
        const double yy1 = fmax(y1, jb[jj][0]);
        const double xx1 = fmax(x1, jb[jj][1]);
        const double yy2 = fmin(y2, jb[jj][2]);
        const double xx2 = fmin(x2, jb[jj][3]);
        const double ih = fmax(yy2 - yy1, 0.0);
        const double iw = fmax(xx2 - xx1, 0.0);
        const double inter = ih * iw;
        const double a2 = (jb[jj][2] - jb[jj][0]) * (jb[jj][3] - jb[jj][1]);
        const double iou = inter / (a1 + a2 - inter + 1e-9);
        if (iou > 0.7) wbits |= (1ULL << jj);
    }
    mask[(size_t)i * MW + bj] = wbits;
}

// ---------------- K6: greedy scan with 4-deep speculative row prefetch.
// Exact greedy-by-index (== argmax over descending-sorted scores): each round takes
// the 4 lowest available candidates, loads their mask rows CONCURRENTLY (one global
// latency instead of four), then resolves mutual suppression in-register.
__global__ __launch_bounds__(64) void nms_k(const double* __restrict__ boxes64, const double* __restrict__ nsc,
                                            const unsigned long long* __restrict__ mask, float* __restrict__ out_boxes) {
    __shared__ unsigned long long flags[MW], supp[MW];
    const int lane = threadIdx.x;
    for (int w = lane; w < MW; w += 64) supp[w] = 0ULL;
    for (int w = 0; w < MW; ++w) {
        int idx = w * 64 + lane;
        bool v = (idx < NB) && (nsc[idx] > -5.0e8);
        unsigned long long b = __ballot(v);
        if (lane == 0) flags[w] = b;
    }
    __syncthreads();
    int nk = 0;
    for (int w = 0; w < MW && nk < NA; ++w) {
        unsigned long long done = 0ULL;
        for (;;) {
            if (nk >= NA) break;
            unsigned long long avail = flags[w] & ~supp[w] & ~done;
            if (!avail) break;
            // pick up to 4 lowest set bits (global candidate indices, ascending)
            int c[4]; int n = 0;
            unsigned long long t = avail;
            while (n < 4 && t) { int b = __builtin_ctzll(t); c[n] = w * 64 + b; ++n; t &= t - 1; }
            unsigned long long dmask = 0ULL;
            for (int q = 0; q < n; ++q) dmask |= 1ULL << (c[q] & 63);
            done |= dmask;
            // issue all row loads up front (lane holds words lane and lane+64 of each row)
            unsigned long long r0[4], r1[4];
            #pragma unroll
            for (int q = 0; q < 4; ++q) {
                int qq = (q < n) ? q : 0;
                r0[q] = mask[(size_t)c[qq] * MW + lane];
                r1[q] = (lane + 64 < MW) ? mask[(size_t)c[qq] * MW + lane + 64] : 0ULL;
            }
            // concurrently load the 4 candidate boxes (lane q*4+coord, lane<16)
            double bxv = 0.0;
            if (lane < 16) {
                int q = lane >> 2;
                int qq = (q < n) ? q : 0;
                bxv = boxes64[(size_t)c[qq] * 4 + (lane & 3)];
            }
            // bit j of row q (q literal): word j>>6 lives on lane (j>>6)&63, reg r0/r1
            auto rowbit = [&](int q, int j) -> int {
                int qw = j >> 6;
                unsigned long long word = (qw < 64) ? r0[q] : r1[q];
                int holder = (qw < 64) ? qw : (qw - 64);
                unsigned long long wv = __shfl(word, holder);
                return (int)((wv >> (j & 63)) & 1ULL);
            };
            // exact greedy resolution among c[0..n): c0 always selected
            int sel[4] = {1, 0, 0, 0};
            if (n > 1) sel[1] = !rowbit(0, c[1]);
            if (n > 2) sel[2] = !(rowbit(0, c[2]) || (sel[1] && rowbit(1, c[2])));
            if (n > 3) sel[3] = !(rowbit(0, c[3]) || (sel[1] && rowbit(1, c[3]))
                                  || (sel[2] && rowbit(2, c[3])));
            int outpos[4]; int nsel = 0;
            for (int q = 0; q < n; ++q) { outpos[q] = nk + nsel; if (sel[q]) ++nsel; }
            if (lane < 16) {
                int q = lane >> 2;
                if (q < n && sel[q] && outpos[q] < NA)
                    out_boxes[outpos[q] * 4 + (lane & 3)] = (float)bxv;
            }
            unsigned long long o0 = 0ULL, o1 = 0ULL;
            for (int q = 0; q < n; ++q) if (sel[q]) { o0 |= r0[q]; o1 |= r1[q]; }
            supp[lane] |= o0;
            if (lane + 64 < MW) supp[lane + 64] |= o1;
            nk += nsel;
        }
    }
    for (int k = nk; k < NA; ++k)
        if (lane < 4) out_boxes[k * 4 + lane] = 0.f;
}

extern "C" void kernel_launch(void* const* d_in, const int* in_sizes, int n_in,
                              void* d_out, int out_size, void* d_ws, size_t ws_size,
                              hipStream_t stream) {
    (void)in_sizes; (void)n_in; (void)out_size; (void)ws_size;
    const float* x       = (const float*)d_in[0];
    const float* anchors = (const float*)d_in[1];
    const float* conv1_w = (const float*)d_in[2];
    const float* conv1_b = (const float*)d_in[3];
    const float* cls_w   = (const float*)d_in[4];
    const float* cls_b   = (const float*)d_in[5];
    const float* bbox_w  = (const float*)d_in[6];
    const float* bbox_b  = (const float*)d_in[7];
    float* out = (float*)d_out;
    float* out_scores = out;             // 147456
    float* out_regs   = out + NN;        // 589824
    float* out_boxes  = out + NN * 5;    // 1200 @ 737280

    char* ws = (char*)d_ws;
    // Overlay region inside the h64 footprint; only used after heads_k (h dead).
    // ckey overlays the mask region (consumed before the mask memset).
    unsigned int* hist        = (unsigned int*)(ws + 0);            // 16384 B
    unsigned int* cut         = (unsigned int*)(ws + 16384);        // 64 B
    unsigned int* cnt         = (unsigned int*)(ws + 16640);        // 256 B
    unsigned int* cand        = (unsigned int*)(ws + 16896);        // 32768 B
    unsigned int* topi        = (unsigned int*)(ws + 49664);        // 24064 B
    double*       boxes64     = (double*)(ws + 73728);              // 192000 B
    double*       nsc         = (double*)(ws + 265728);             // 48000 B
    unsigned long long* mask  = (unsigned long long*)(ws + 313856); // 4512000 B
    unsigned long long* ckey  = (unsigned long long*)(ws + 313856); // 65536 B (pre-memset lifetime)
    double* h64 = (double*)(ws + 0);                                // 33554432 B
    float*  wT  = (float*)(ws + 33554432);                          // 2359296 B
    double* s64 = (double*)(ws + 35913728);                         // 1179648 B
    double* r64 = (double*)(ws + 37093376);                         // 4718592 B

    prep_w_k<<<2304, 256, 0, stream>>>(conv1_w, wT);
    conv3_k<<<1024, 256, 0, stream>>>(x, wT, conv1_b, h64);
    heads_k<<<256, 1024, 0, stream>>>(h64, cls_w, cls_b, bbox_w, bbox_b,
                                      out_scores, out_regs, s64, r64);
    // h64 is dead from here; overlay region becomes valid.
    hipMemsetAsync(cnt, 0, 4, stream);
    for (int pass = 0; pass < 3; ++pass) {
        hipMemsetAsync(hist, 0, 16384, stream);
        hist_k<<<144, 1024, 0, stream>>>(s64, hist, cut, pass);
        scan_k<<<1, 64, 0, stream>>>(hist, cut, pass);
    }
    gather_k<<<144, 1024, 0, stream>>>(s64, cut, cnt, cand);
    pack_k<<<32, 256, 0, stream>>>(s64, cand, cnt, ckey);
    rank2_k<<<2048, 256, 0, stream>>>(ckey, cand, cnt, topi);
    decode_k<<<24, 256, 0, stream>>>(anchors, r64, s64, topi, boxes64, nsc);
    hipMemsetAsync(mask, 0, (size_t)NB * MW * 8, stream);   // kills ckey (already consumed)
    iou_k<<<dim3(MW, MW), 64, 0, stream>>>(boxes64, mask);
    nms_k<<<1, 64, 0, stream>>>(boxes64, nsc, mask, out_boxes);
}

// Round 6
// 1083.160 us; speedup vs baseline: 2.2601x; 1.0417x over previous
//
#include <hip/hip_runtime.h>
#include <cmath>

#define NN 147456     // H*W*A
#define NPX 16384     // H*W
#define NB 6000       // before_proposal_num
#define NA 300        // after_proposal_num
#define MW 94         // ceil(6000/64)

// ---------------- K0: weight permute wT2[k][co] (k=ci*9+tap, co global) + zero ghist/cnt
__global__ __launch_bounds__(256) void prep_w_k(const float* __restrict__ w, float* __restrict__ wT2,
                                                unsigned int* __restrict__ ghist, unsigned int* __restrict__ cnt) {
    if (blockIdx.x == 0) {
        for (int i = threadIdx.x; i < 4096; i += 256) ghist[i] = 0;
        if (threadIdx.x == 0) cnt[0] = 0;
    }
    int idx = blockIdx.x * 256 + threadIdx.x;
    if (idx >= 2304 * 256) return;
    int co = idx & 255;
    int k  = idx >> 8;
    int ci = k / 9, tap = k - 9 * ci;
    wT2[idx] = w[(co * 256 + ci) * 9 + tap];
}

// ---------------- K1: 3x3 conv, fp64 fma, FMA order bit-identical to round 5.
// 128 threads/block, thread = 4co x 8px (full row): cvt/FMA 0.375 -> 0.23.
// b128-aligned LDS ([72][64] w; x rows padded to 12), float4 w-staging,
// T14 reg-prefetch of chunk k+1 during compute of chunk k. Grid 1024 (XCD-swizzled).
__global__ __launch_bounds__(128) void conv3_k(const float* __restrict__ x, const float* __restrict__ wT2,
                                               const float* __restrict__ bias, double* __restrict__ h64) {
    __shared__ __align__(16) float xtf[960];     // [ci][10][12]
    __shared__ __align__(16) float wl[4608];     // [kl][co64]
    const int bx = blockIdx.x;
    const int tile = ((bx >> 5) << 3) | (bx & 7);
    const int g = (bx >> 3) & 3;
    const int ty0 = (tile >> 4) << 3;
    const int tx0 = (tile & 15) << 3;
    const int tid = threadIdx.x;
    const int qc = tid & 15;      // co-quad (4 couts)
    const int py = tid >> 4;      // row 0..7 (8 px)

    // staging descriptors (chunk-independent)
    int xga[7], xlo[7]; bool xin[7], xwr[7];
    #pragma unroll
    for (int r = 0; r < 7; ++r) {
        int l = tid + r * 128;
        xwr[r] = (l < 800);
        int ci = l / 100; int rem = l - ci * 100;
        int rr = rem / 10; int cc = rem - rr * 10;
        int gy = ty0 + rr - 1, gx = tx0 + cc - 1;
        xin[r] = xwr[r] && gy >= 0 && gy < 128 && gx >= 0 && gx < 128;
        xga[r] = ci * NPX + gy * 128 + gx;
        xlo[r] = ci * 120 + rr * 12 + cc;
    }
    const float* wbase = wT2 + (g << 6);
    int wga[9];
    #pragma unroll
    for (int r = 0; r < 9; ++r) {
        int f = tid + r * 128;                       // float4 index 0..1151
        wga[r] = ((f >> 4) << 8) + ((f & 15) << 2);  // kl*256 + cof
    }

    float xreg[7]; float4 wreg[9];
    #pragma unroll
    for (int r = 0; r < 7; ++r) { float v = 0.f; if (xin[r]) v = x[xga[r]]; xreg[r] = v; }
    #pragma unroll
    for (int r = 0; r < 9; ++r) wreg[r] = *(const float4*)(wbase + wga[r]);

    double acc[4][8];
    #pragma unroll
    for (int a = 0; a < 4; ++a)
        #pragma unroll
        for (int b = 0; b < 8; ++b) acc[a][b] = 0.0;

    for (int ch = 0; ch < 32; ++ch) {
        __syncthreads();
        #pragma unroll
        for (int r = 0; r < 7; ++r) if (xwr[r]) xtf[xlo[r]] = xreg[r];
        #pragma unroll
        for (int r = 0; r < 9; ++r) *(float4*)&wl[(tid + r * 128) << 2] = wreg[r];
        __syncthreads();
        if (ch < 31) {   // T14: issue next chunk's loads; vmcnt waited at next ds_write
            const float* xp = x + (size_t)(ch + 1) * (8 * NPX);
            const float* wp = wbase + (ch + 1) * 18432;
            #pragma unroll
            for (int r = 0; r < 7; ++r) { float v = 0.f; if (xin[r]) v = xp[xga[r]]; xreg[r] = v; }
            #pragma unroll
            for (int r = 0; r < 9; ++r) wreg[r] = *(const float4*)(wp + wga[r]);
        }
        for (int ci = 0; ci < 8; ++ci) {
            #pragma unroll
            for (int dy = 0; dy < 3; ++dy) {
                double xr[10];
                #pragma unroll
                for (int j = 0; j < 10; ++j) xr[j] = (double)xtf[ci * 120 + (py + dy) * 12 + j];
                #pragma unroll
                for (int dx = 0; dx < 3; ++dx) {
                    double wv[4];
                    #pragma unroll
                    for (int co = 0; co < 4; ++co)
                        wv[co] = (double)wl[((ci * 9 + dy * 3 + dx) << 6) + (qc << 2) + co];
                    #pragma unroll
                    for (int co = 0; co < 4; ++co)
                        #pragma unroll
                        for (int p = 0; p < 8; ++p)
                            acc[co][p] = fma(wv[co], xr[p + dx], acc[co][p]);
                }
            }
        }
    }
    const int oy = ty0 + py;
    #pragma unroll
    for (int co = 0; co < 4; ++co) {
        int oc = (g << 6) + (qc << 2) + co;
        double b = (double)bias[oc];
        #pragma unroll
        for (int p = 0; p < 8; ++p) {
            double v = acc[co][p] + b;
            h64[(size_t)oc * NPX + oy * 128 + tx0 + p] = v > 0.0 ? v : 0.0;
        }
    }
}

// ---------------- K2: 1x1 heads (fp64) + sigmoid + FUSED pass-0 score histogram
__global__ __launch_bounds__(1024) void heads_k(const double* __restrict__ h64,
        const float* __restrict__ cls_w, const float* __restrict__ cls_b,
        const float* __restrict__ bbox_w, const float* __restrict__ bbox_b,
        float* __restrict__ out_scores, float* __restrict__ out_regs,
        double* __restrict__ scores64, double* __restrict__ regs64,
        unsigned int* __restrict__ ghist) {
    __shared__ float wlh[45 * 256];
    __shared__ unsigned int lh[4096];
    const int tid = threadIdx.x;
    for (int l = tid; l < 45 * 256; l += 1024)
        wlh[l] = (l < 2304) ? cls_w[l] : bbox_w[l - 2304];
    for (int i = tid; i < 4096; i += 1024) lh[i] = 0;
    __syncthreads();
    const int w = tid >> 6;
    const int lane = tid & 63;
    const int px = blockIdx.x * 64 + lane;
    const int o0 = w, o1 = w + 16, o2 = w + 32;
    const bool has2 = (o2 < 45);
    double a0 = 0.0, a1 = 0.0, a2 = 0.0;
    const float* w0 = wlh + o0 * 256;
    const float* w1 = wlh + o1 * 256;
    const float* w2 = wlh + (has2 ? o2 : 0) * 256;
    for (int c = 0; c < 256; ++c) {
        double hv = h64[(size_t)c * NPX + px];
        a0 = fma(hv, (double)w0[c], a0);
        a1 = fma(hv, (double)w1[c], a1);
        if (has2) a2 = fma(hv, (double)w2[c], a2);
    }
    auto emit = [&](int o, double acc) {
        if (o < 9) {
            acc += (double)cls_b[o];
            double s = 1.0 / (1.0 + exp(-acc));
            out_scores[px * 9 + o] = (float)s;
            scores64[px * 9 + o] = s;
            atomicAdd(&lh[(unsigned int)((unsigned long long)__double_as_longlong(s) >> 52)], 1u);
        } else {
            acc += (double)bbox_b[o - 9];
            out_regs[px * 36 + (o - 9)] = (float)acc;
            regs64[px * 36 + (o - 9)] = acc;
        }
    };
    emit(o0, a0);
    emit(o1, a1);
    if (has2) emit(o2, a2);
    __syncthreads();
    for (int i = tid; i < 4096; i += 1024) {
        unsigned int v = lh[i];
        if (v) atomicAdd(&ghist[i], v);
    }
}

// ---------------- K3: radix histogram passes 1,2 on fp64 score bits
__global__ __launch_bounds__(1024) void hist_k(const double* __restrict__ s64, unsigned int* __restrict__ ghist,
                                               const unsigned int* __restrict__ cut, int pass) {
    __shared__ unsigned int lh[4096];
    const int tid = threadIdx.x;
    for (int i = tid; i < 4096; i += 1024) lh[i] = 0;
    __syncthreads();
    const int gid = blockIdx.x * 1024 + tid;
    unsigned long long bits = (unsigned long long)__double_as_longlong(s64[gid]);
    bool ok; unsigned int bucket;
    if (pass == 1) {
        ok = ((unsigned int)(bits >> 52) == cut[0]);
        bucket = (unsigned int)(bits >> 40) & 0xFFFu;
    } else {
        ok = (((unsigned int)(bits >> 40) & 0xFFFFFFu) == ((cut[0] << 12) | cut[2]));
        bucket = (unsigned int)(bits >> 28) & 0xFFFu;
    }
    if (ok) atomicAdd(&lh[bucket], 1u);
    __syncthreads();
    for (int i = tid; i < 4096; i += 1024) {
        unsigned int v = lh[i];
        if (v) atomicAdd(&ghist[i], v);
    }
}

// single-wave descending scan; zeroes hist for the next pass
__global__ __launch_bounds__(64) void scan_k(unsigned int* __restrict__ hist,
                                             unsigned int* __restrict__ cut, int pass) {
    const int lane = threadIdx.x;
    unsigned int running = (pass == 0) ? 0u : cut[2 * pass - 1];
    unsigned int resb = 0xFFFFFFFFu, resc = 0u;
    for (int it = 0; it < 64; ++it) {
        int b = 4095 - (it * 64 + lane);
        unsigned int c = hist[b];
        unsigned int inc = c;
        #pragma unroll
        for (int d = 1; d < 64; d <<= 1) {
            unsigned int o = __shfl_up(inc, d);
            if (lane >= d) inc += o;
        }
        unsigned long long mb = __ballot(running + inc >= (unsigned int)NB);
        if (mb != 0ULL) {
            int first = __builtin_ctzll(mb);
            if (lane == first) { resb = (unsigned int)b; resc = running + inc - c; }
            break;
        }
        running += __shfl(inc, 63);
    }
    for (int i = lane; i < 4096; i += 64) hist[i] = 0;
    unsigned long long anyf = __ballot(resb != 0xFFFFFFFFu);
    if (anyf == 0ULL) {
        if (lane == 0) { cut[2 * pass] = 0; cut[2 * pass + 1] = 0; }
    } else if (resb != 0xFFFFFFFFu) {
        cut[2 * pass] = resb; cut[2 * pass + 1] = resc;
    }
}

// gather candidates + pack keys (fused old pack_k)
__global__ __launch_bounds__(1024) void gather_k(const double* __restrict__ s64, const unsigned int* __restrict__ cut,
                                                 unsigned int* __restrict__ counter, unsigned int* __restrict__ cand,
                                                 unsigned long long* __restrict__ ckey) {
    const int gid = blockIdx.x * 1024 + threadIdx.x;
    unsigned long long bits = (unsigned long long)__double_as_longlong(s64[gid]);
    unsigned long long k36 = (bits >> 28) & 0xFFFFFFFFFULL;
    unsigned long long T = ((unsigned long long)((cut[0] << 12) | cut[2]) << 12) | (unsigned long long)cut[4];
    if (k36 >= T) {
        unsigned int p = atomicAdd(counter, 1u);
        if (p < 8192) { cand[p] = (unsigned int)gid; ckey[p] = bits; }
    }
}

// exact rank-select (key desc, idx asc), one candidate per wave, FUSED decode on lane 0
__global__ __launch_bounds__(256) void rank2_k(const unsigned long long* __restrict__ ckey,
        const unsigned int* __restrict__ cand, const unsigned int* __restrict__ counter,
        const float* __restrict__ anchors, const double* __restrict__ r64,
        double* __restrict__ boxes64, double* __restrict__ nsc) {
    int M = (int)*counter; if (M > 8192) M = 8192;
    const int wid = (blockIdx.x * 256 + threadIdx.x) >> 6;
    const int lane = threadIdx.x & 63;
    if (wid >= M) return;
    const unsigned long long myk = ckey[wid];
    const unsigned int myv = cand[wid];
    int cntv = 0;
    for (int l = lane; l < M; l += 64) {
        unsigned long long kk = ckey[l];
        unsigned int vv = cand[l];
        if (kk > myk || (kk == myk && vv < myv)) ++cntv;
    }
    #pragma unroll
    for (int dd = 32; dd; dd >>= 1) cntv += __shfl_down(cntv, dd);
    if (lane == 0 && cntv < NB) {
        const int rk = cntv;
        const int i = (int)myv;
        const int px = i / 9, a = i - 9 * px;
        const float* an = anchors + px * 36 + a * 4;
        const double* d = r64 + px * 36 + a * 4;
        const double acy = (double)an[0], acx = (double)an[1], ah = (double)an[2], aw = (double)an[3];
        const double cy = acy + d[0] * ah;
        const double cx = acx + d[1] * aw;
        const double bh = ah * exp(d[2]);
        const double bw = aw * exp(d[3]);
        double y1 = cy - 0.5 * bh, x1 = cx - 0.5 * bw;
        double y2 = cy + 0.5 * bh, x2 = cx + 0.5 * bw;
        y1 = fmax(y1, 0.0); x1 = fmax(x1, 0.0);
        y2 = fmin(y2, 2048.0); x2 = fmin(x2, 2048.0);
        boxes64[rk * 4 + 0] = y1; boxes64[rk * 4 + 1] = x1;
        boxes64[rk * 4 + 2] = y2; boxes64[rk * 4 + 3] = x2;
        double s = __longlong_as_double((long long)myk);
        if (!(((y2 - y1) >= 16.0) && ((x2 - x1) >= 16.0))) s = -1.0e9;
        nsc[rk] = s;
    }
}

// ---------------- K5: suppression bitmask; lower-triangle blocks write zeros (no memset)
__global__ __launch_bounds__(64) void iou_k(const double* __restrict__ boxes64, unsigned long long* __restrict__ mask) {
    const int bi = blockIdx.x, bj = blockIdx.y;
    const int t = threadIdx.x;
    const int i = bi * 64 + t;
    if (bj < bi) {
        if (i < NB) mask[(size_t)i * MW + bj] = 0ULL;
        return;
    }
    __shared__ double jb[64][4];
    const int j0 = bj * 64;
    const int jn = min(64, NB - j0);
    if (t < jn) {
        jb[t][0] = boxes64[(j0 + t) * 4 + 0];
        jb[t][1] = boxes64[(j0 + t) * 4 + 1];
        jb[t][2] = boxes64[(j0 + t) * 4 + 2];
        jb[t][3] = boxes64[(j0 + t) * 4 + 3];
    }
    __syncthreads();
    if (i >= NB) return;
    const double y1 = boxes64[i * 4 + 0], x1 = boxes64[i * 4 + 1];
    const double y2 = boxes64[i * 4 + 2], x2 = boxes64[i * 4 + 3];
    const double a1 = (y2 - y1) * (x2 - x1);
    unsigned long long wbits = 0ULL;
    for (int jj = 0; jj < jn; ++jj) {
        const int j = j0 + jj;
        if (j <= i) continue;
        const double yy1 = fmax(y1, jb[jj][0]);
        const double xx1 = fmax(x1, jb[jj][1]);
        const double yy2 = fmin(y2, jb[jj][2]);
        const double xx2 = fmin(x2, jb[jj][3]);
        const double ih = fmax(yy2 - yy1, 0.0);
        const double iw = fmax(xx2 - xx1, 0.0);
        const double inter = ih * iw;
        const double a2 = (jb[jj][2] - jb[jj][0]) * (jb[jj][3] - jb[jj][1]);
        const double iou = inter / (a1 + a2 - inter + 1e-9);
        if (iou > 0.7) wbits |= (1ULL << jj);
    }
    mask[(size_t)i * MW + bj] = wbits;
}

// ---------------- K6: greedy scan, 4-deep speculative row prefetch (round-5 proven)
__global__ __launch_bounds__(64) void nms_k(const double* __restrict__ boxes64, const double* __restrict__ nsc,
                                            const unsigned long long* __restrict__ mask, float* __restrict__ out_boxes) {
    __shared__ unsigned long long flags[MW], supp[MW];
    const int lane = threadIdx.x;
    for (int w = lane; w < MW; w += 64) supp[w] = 0ULL;
    for (int w = 0; w < MW; ++w) {
        int idx = w * 64 + lane;
        bool v = (idx < NB) && (nsc[idx] > -5.0e8);
        unsigned long long b = __ballot(v);
        if (lane == 0) flags[w] = b;
    }
    __syncthreads();
    int nk = 0;
    for (int w = 0; w < MW && nk < NA; ++w) {
        unsigned long long done = 0ULL;
        for (;;) {
            if (nk >= NA) break;
            unsigned long long avail = flags[w] & ~supp[w] & ~done;
            if (!avail) break;
            int c[4]; int n = 0;
            unsigned long long t = avail;
            while (n < 4 && t) { int b = __builtin_ctzll(t); c[n] = w * 64 + b; ++n; t &= t - 1; }
            unsigned long long dmask = 0ULL;
            for (int q = 0; q < n; ++q) dmask |= 1ULL << (c[q] & 63);
            done |= dmask;
            unsigned long long r0[4], r1[4];
            #pragma unroll
            for (int q = 0; q < 4; ++q) {
                int qq = (q < n) ? q : 0;
                r0[q] = mask[(size_t)c[qq] * MW + lane];
                r1[q] = (lane + 64 < MW) ? mask[(size_t)c[qq] * MW + lane + 64] : 0ULL;
            }
            double bxv = 0.0;
            if (lane < 16) {
                int q = lane >> 2;
                int qq = (q < n) ? q : 0;
                bxv = boxes64[(size_t)c[qq] * 4 + (lane & 3)];
            }
            auto rowbit = [&](int q, int j) -> int {
                int qw = j >> 6;
                unsigned long long word = (qw < 64) ? r0[q] : r1[q];
                int holder = (qw < 64) ? qw : (qw - 64);
                unsigned long long wv = __shfl(word, holder);
                return (int)((wv >> (j & 63)) & 1ULL);
            };
            int sel[4] = {1, 0, 0, 0};
            if (n > 1) sel[1] = !rowbit(0, c[1]);
            if (n > 2) sel[2] = !(rowbit(0, c[2]) || (sel[1] && rowbit(1, c[2])));
            if (n > 3) sel[3] = !(rowbit(0, c[3]) || (sel[1] && rowbit(1, c[3]))
                                  || (sel[2] && rowbit(2, c[3])));
            int outpos[4]; int nsel = 0;
            for (int q = 0; q < n; ++q) { outpos[q] = nk + nsel; if (sel[q]) ++nsel; }
            if (lane < 16) {
                int q = lane >> 2;
                if (q < n && sel[q] && outpos[q] < NA)
                    out_boxes[outpos[q] * 4 + (lane & 3)] = (float)bxv;
            }
            unsigned long long o0 = 0ULL, o1 = 0ULL;
            for (int q = 0; q < n; ++q) if (sel[q]) { o0 |= r0[q]; o1 |= r1[q]; }
            supp[lane] |= o0;
            if (lane + 64 < MW) supp[lane + 64] |= o1;
            nk += nsel;
        }
    }
    for (int k = nk; k < NA; ++k)
        if (lane < 4) out_boxes[k * 4 + lane] = 0.f;
}

extern "C" void kernel_launch(void* const* d_in, const int* in_sizes, int n_in,
                              void* d_out, int out_size, void* d_ws, size_t ws_size,
                              hipStream_t stream) {
    (void)in_sizes; (void)n_in; (void)out_size; (void)ws_size;
    const float* x       = (const float*)d_in[0];
    const float* anchors = (const float*)d_in[1];
    const float* conv1_w = (const float*)d_in[2];
    const float* conv1_b = (const float*)d_in[3];
    const float* cls_w   = (const float*)d_in[4];
    const float* cls_b   = (const float*)d_in[5];
    const float* bbox_w  = (const float*)d_in[6];
    const float* bbox_b  = (const float*)d_in[7];
    float* out = (float*)d_out;
    float* out_scores = out;             // 147456
    float* out_regs   = out + NN;        // 589824
    float* out_boxes  = out + NN * 5;    // 1200 @ 737280

    char* ws = (char*)d_ws;
    // h64 overlay (valid after heads_k): cut, cand, boxes64, nsc, mask/ckey.
    unsigned int*       cut     = (unsigned int*)(ws + 0);          // 64 B
    unsigned int*       cand    = (unsigned int*)(ws + 256);        // 32768 B
    double*             boxes64 = (double*)(ws + 33024);            // 192000 B
    double*             nsc     = (double*)(ws + 225024);           // 48000 B
    unsigned long long* mask    = (unsigned long long*)(ws + 273024); // 4512000 B
    unsigned long long* ckey    = (unsigned long long*)(ws + 273024); // 65536 B (consumed before iou_k writes mask)
    double* h64 = (double*)(ws + 0);                                // 33554432 B
    float*  wT2 = (float*)(ws + 33554432);                          // 2359296 B
    double* s64 = (double*)(ws + 35913728);                         // 1179648 B
    double* r64 = (double*)(ws + 37093376);                         // 4718592 B
    // outside h64 (live during conv/heads):
    unsigned int* ghist = (unsigned int*)(ws + 41811968);           // 16384 B
    unsigned int* cnt   = (unsigned int*)(ws + 41828352);           // 256 B

    prep_w_k<<<2304, 256, 0, stream>>>(conv1_w, wT2, ghist, cnt);
    conv3_k<<<1024, 128, 0, stream>>>(x, wT2, conv1_b, h64);
    heads_k<<<256, 1024, 0, stream>>>(h64, cls_w, cls_b, bbox_w, bbox_b,
                                      out_scores, out_regs, s64, r64, ghist);
    // h64 dead from here.
    scan_k<<<1, 64, 0, stream>>>(ghist, cut, 0);
    hist_k<<<144, 1024, 0, stream>>>(s64, ghist, cut, 1);
    scan_k<<<1, 64, 0, stream>>>(ghist, cut, 1);
    hist_k<<<144, 1024, 0, stream>>>(s64, ghist, cut, 2);
    scan_k<<<1, 64, 0, stream>>>(ghist, cut, 2);
    gather_k<<<144, 1024, 0, stream>>>(s64, cut, cnt, cand, ckey);
    rank2_k<<<2048, 256, 0, stream>>>(ckey, cand, cnt, anchors, r64, boxes64, nsc);
    iou_k<<<dim3(MW, MW), 64, 0, stream>>>(boxes64, mask);
    nms_k<<<1, 64, 0, stream>>>(boxes64, nsc, mask, out_boxes);
}